// Round 10
// baseline (196.308 us; speedup 1.0000x reference)
//
#include <hip/hip_runtime.h>

#define B_ 4
#define C_ 256
#define H_ 64
#define W_ 64
#define HW_ 4096
#define CO_ 256
#define NPX_ 16384
#define GN_EPS_ 1e-5f

typedef float f32x4 __attribute__((ext_vector_type(4)));
typedef short s16x8 __attribute__((ext_vector_type(8)));

__device__ __forceinline__ short f2bf(float f) {
    union { float f; unsigned u; } v; v.f = f;
    unsigned r = (v.u + 0x7FFFu + ((v.u >> 16) & 1u)) >> 16;
    return (short)(r & 0xFFFFu);
}
__device__ __forceinline__ float bf2f(short s) {
    union { unsigned u; float f; } v; v.u = ((unsigned)s & 0xFFFFu) << 16;
    return v.f;
}

__device__ __forceinline__ void gld_lds16(const void* g, void* l) {
    __builtin_amdgcn_global_load_lds(
        (const __attribute__((address_space(1))) unsigned*)g,
        (__attribute__((address_space(3))) unsigned*)l,
        16, 0, 0);
}

// ---------------- K0: w[oc][c][kk] -> wT[kk][oc][c] bf16 ----------------
__global__ void k_prep_w(const float* __restrict__ w, short* __restrict__ wT) {
    int oc = blockIdx.x, c = threadIdx.x;
    const float* src = w + (oc * 256 + c) * 9;
    float v[9];
#pragma unroll
    for (int t = 0; t < 9; ++t) v[t] = src[t];
#pragma unroll
    for (int t = 0; t < 9; ++t) wT[(t * 256 + oc) * 256 + c] = f2bf(v[t]);
}

// ---------------- K0a: w_off -> wOffT[kk][32][256] bf16 (rows 27..31 zero) ----
__global__ void k_prep_woff(const float* __restrict__ w_off, short* __restrict__ wOffT) {
    int o = blockIdx.x;
    int c = threadIdx.x;
    if (o < 27) {
        const float* src = w_off + (o * 256 + c) * 9;
#pragma unroll
        for (int t = 0; t < 9; ++t)
            wOffT[(t * 32 + o) * 256 + c] = f2bf(src[t]);
    } else {
#pragma unroll
        for (int t = 0; t < 9; ++t)
            wOffT[(t * 32 + o) * 256 + c] = 0;
    }
}

// ---------------- K0b: x[b][c][hw] f32 -> xT[b][hw][c] bf16 ----------------
__global__ void k_xpose(const float* __restrict__ x, short* __restrict__ xT) {
    __shared__ short T[64 * 72];

    int bx  = blockIdx.x;
    int px0 = (bx & 255) * 64;
    int c0  = (bx >> 8) * 64;
    int b   = px0 >> 12;
    int hw0 = px0 & 4095;

    int t  = threadIdx.x;
    int cl = t & 63;
    int q  = t >> 6;

    const float4* src = reinterpret_cast<const float4*>(
        x + (long)(b * 256 + c0 + cl) * 4096 + hw0);
#pragma unroll
    for (int j = 0; j < 4; ++j) {
        float4 v = src[j * 4 + q];
        int pl = (j * 4 + q) * 4;
        T[(pl + 0) * 72 + cl] = f2bf(v.x);
        T[(pl + 1) * 72 + cl] = f2bf(v.y);
        T[(pl + 2) * 72 + cl] = f2bf(v.z);
        T[(pl + 3) * 72 + cl] = f2bf(v.w);
    }
    __syncthreads();

    int pl = t >> 2;
    int s  = t & 3;
    short* dst = xT + (long)(px0 + pl) * 256 + c0 + s * 16;
    s16x8 a    = *reinterpret_cast<const s16x8*>(&T[pl * 72 + s * 16]);
    s16x8 bseg = *reinterpret_cast<const s16x8*>(&T[pl * 72 + s * 16 + 8]);
    *reinterpret_cast<s16x8*>(dst)     = a;
    *reinterpret_cast<s16x8*>(dst + 8) = bseg;
}

// ---------------- K1: offset conv via MFMA, K-split x4 ----------------
__global__ __launch_bounds__(256, 4) void k_offmfma(
        const short* __restrict__ xT, const short* __restrict__ wOffT,
        float* __restrict__ offp) {
    int tid  = threadIdx.x;
    int lane = tid & 63;
    int wv   = tid >> 6;

    int px0  = blockIdx.x * 64 + wv * 16;
    int cc0  = blockIdx.y * 64;
    int lm   = lane & 15;
    int lk   = cc0 + (lane >> 4) * 8;

    int pxA = px0 + lm;
    int h   = (pxA >> 6) & 63;
    int w   = pxA & 63;

    f32x4 acc[2];
    acc[0] = (f32x4)0.f; acc[1] = (f32x4)0.f;

#pragma unroll
    for (int kk = 0; kk < 9; ++kk) {
        const int ki = kk / 3, kj = kk % 3;
        int hh = h + ki - 1, ww = w + kj - 1;
        bool valid = ((unsigned)hh < 64u) & ((unsigned)ww < 64u);
        int srcpx = valid ? (pxA + (ki - 1) * 64 + (kj - 1)) : 0;
        const short* aP = xT + (long)srcpx * 256 + lk;
        const short* bP = wOffT + (long)(kk * 32 + lm) * 256 + lk;
#pragma unroll
        for (int ks = 0; ks < 2; ++ks) {
            s16x8 a = *reinterpret_cast<const s16x8*>(aP + ks * 32);
            if (!valid) a = (s16x8)0;
            s16x8 b0 = *reinterpret_cast<const s16x8*>(bP + ks * 32);
            s16x8 b1 = *reinterpret_cast<const s16x8*>(bP + 16 * 256 + ks * 32);
            acc[0] = __builtin_amdgcn_mfma_f32_16x16x32_bf16(a, b0, acc[0], 0, 0, 0);
            acc[1] = __builtin_amdgcn_mfma_f32_16x16x32_bf16(a, b1, acc[1], 0, 0, 0);
        }
    }

    float* op = offp + (long)blockIdx.y * 27 * NPX_;
#pragma unroll
    for (int nt = 0; nt < 2; ++nt) {
        int oc = nt * 16 + lm;
        if (oc < 27) {
#pragma unroll
            for (int j = 0; j < 4; ++j) {
                int px = px0 + (lane >> 4) * 4 + j;
                op[oc * NPX_ + px] = acc[nt][j];
            }
        }
    }
}

// ---------------- K1b: reduce K-split partials + bias ----------------
__global__ void k_offreduce(const float* __restrict__ offp, const float* __restrict__ b_off,
                            float* __restrict__ off) {
    int idx = blockIdx.x * 256 + threadIdx.x;
    int oc  = idx >> 14;
    float s = b_off[oc];
#pragma unroll
    for (int j = 0; j < 4; ++j) s += offp[(long)j * 27 * NPX_ + idx];
    off[idx] = s;
}

// ---------------- K2: FUSED sample + MFMA GEMM, BK=32, T14 pipeline ----------------
// grid 256: bid = pxt (64-px row). 512 thr = 8 waves. 2 blocks/CU (41 KB LDS).
// 72 K-tiles: t -> kk = t>>3, cq = t&7 (32-c slice).
// A (64px x 32c, 4KB): threads 0..255 reg-load xT rows (ISSUE), blend+ds_write (WRITE).
// B (256oc x 32c, 16KB): global_load_lds, source pre-swizzled.
// Per tile: ISSUE(t+1) -> COMPUTE(t) -> WRITE(t+1) -> barrier.
__global__ __launch_bounds__(512, 4) void k_fused(
        const short* __restrict__ xT, const float* __restrict__ off,
        const short* __restrict__ wT, const float* __restrict__ bias,
        float* __restrict__ out, float* __restrict__ gnpart) {
    __shared__ __attribute__((aligned(16))) char lds[40960];  // 2 x (A 4K | B 16K)
    __shared__ float red[16];

    int tid  = threadIdx.x;
    int lane = tid & 63;
    int wv   = tid >> 6;

    int px0 = blockIdx.x * 64;
    int b   = px0 >> 12;
    int hw0 = px0 & 4095;
    int h   = hw0 >> 6;
    long rb = (long)b * 4096;

    // sampling role (threads 0..255)
    int spx = tid >> 2;                  // 0..63 (w coordinate)
    int oct = tid & 3;                   // c-octet within 32-c tile
    int pg  = px0 + spx;
    int abyte_w = spx * 64 + ((oct ^ ((spx >> 1) & 3)) << 4);

    // B staging constants
    int brow = lane >> 2;                // row-within-16
    int bq   = lane & 3;

    // mfma role
    int wm = (wv & 1) * 32;
    int wn = (wv >> 1) * 64;
    int lm = lane & 15;
    int kq = lane >> 4;

    const char* wTb = (const char*)wT;

    f32x4 acc[2][4];
#pragma unroll
    for (int i = 0; i < 2; ++i)
#pragma unroll
        for (int j = 0; j < 4; ++j) acc[i][j] = (f32x4)0.f;

    // sampling state (threads 0..255)
    float sw00 = 0.f, sw01 = 0.f, sw10 = 0.f, sw11 = 0.f;
    const short *p00 = xT, *p01 = xT, *p10 = xT, *p11 = xT;
    s16x8 r00, r01, r10, r11;

    // ---- ISSUE(tt, buf): recompute state at kk boundary, issue A reg-loads + B glds ----
#define ISSUE_(tt, buf)                                                              \
    {                                                                                \
        int kk_ = (tt) >> 3, cq_ = (tt) & 7;                                         \
        if ((((tt) & 7) == 0) && tid < 256) {                                        \
            int ki_ = kk_ / 3, kj_ = kk_ % 3;                                        \
            float dy = off[(2 * kk_) * NPX_ + pg];                                   \
            float dx = off[(2 * kk_ + 1) * NPX_ + pg];                               \
            float mk = off[(18 + kk_) * NPX_ + pg];                                  \
            mk = 1.f / (1.f + __expf(-mk));                                          \
            float py  = (float)(h + ki_ - 1) + dy;                                   \
            float pxf = (float)(spx + kj_ - 1) + dx;                                 \
            float y0f = floorf(py), x0f = floorf(pxf);                               \
            float ly = py - y0f, lx = pxf - x0f;                                     \
            int y0 = (int)y0f, x0 = (int)x0f;                                        \
            int y1 = y0 + 1, x1 = x0 + 1;                                            \
            sw00 = (1.f - ly) * (1.f - lx) * mk;                                     \
            sw01 = (1.f - ly) * lx * mk;                                             \
            sw10 = ly * (1.f - lx) * mk;                                             \
            sw11 = ly * lx * mk;                                                     \
            bool vy0 = (y0 >= 0) & (y0 < H_);                                        \
            bool vy1 = (y1 >= 0) & (y1 < H_);                                        \
            bool vx0 = (x0 >= 0) & (x0 < W_);                                        \
            bool vx1 = (x1 >= 0) & (x1 < W_);                                        \
            if (!(vy0 & vx0)) sw00 = 0.f;                                            \
            if (!(vy0 & vx1)) sw01 = 0.f;                                            \
            if (!(vy1 & vx0)) sw10 = 0.f;                                            \
            if (!(vy1 & vx1)) sw11 = 0.f;                                            \
            int cy0 = min(max(y0, 0), H_ - 1), cy1 = min(max(y1, 0), H_ - 1);        \
            int cx0 = min(max(x0, 0), W_ - 1), cx1 = min(max(x1, 0), W_ - 1);        \
            p00 = xT + (rb + cy0 * 64 + cx0) * 256;                                  \
            p01 = xT + (rb + cy0 * 64 + cx1) * 256;                                  \
            p10 = xT + (rb + cy1 * 64 + cx0) * 256;                                  \
            p11 = xT + (rb + cy1 * 64 + cx1) * 256;                                  \
        }                                                                            \
        if (tid < 256) {                                                             \
            int coff = cq_ * 32 + oct * 8;                                           \
            r00 = *reinterpret_cast<const s16x8*>(p00 + coff);                       \
            r01 = *reinterpret_cast<const s16x8*>(p01 + coff);                       \
            r10 = *reinterpret_cast<const s16x8*>(p10 + coff);                       \
            r11 = *reinterpret_cast<const s16x8*>(p11 + coff);                       \
        }                                                                            \
        _Pragma("unroll")                                                            \
        for (int g = 0; g < 2; ++g) {                                                \
            int row = wv * 32 + g * 16 + brow;                                       \
            int qs  = bq ^ ((row >> 1) & 3);                                         \
            const char* srcB = wTb + ((long)(kk_ * 256 + row)) * 512                 \
                               + cq_ * 64 + qs * 16;                                 \
            gld_lds16(srcB, (void*)(lds + (buf) * 20480 + 4096                       \
                                    + (wv * 32 + g * 16) * 64));                     \
        }                                                                            \
    }

    // ---- WRITE(buf): blend regs -> swizzled ds_write ----
#define WRITE_(buf)                                                                  \
    if (tid < 256) {                                                                 \
        s16x8 o8;                                                                    \
        _Pragma("unroll")                                                            \
        for (int jj = 0; jj < 8; ++jj) {                                             \
            float g2 = sw00 * bf2f(r00[jj]) + sw01 * bf2f(r01[jj])                   \
                     + sw10 * bf2f(r10[jj]) + sw11 * bf2f(r11[jj]);                  \
            o8[jj] = f2bf(g2);                                                       \
        }                                                                            \
        *reinterpret_cast<s16x8*>(lds + (buf) * 20480 + abyte_w) = o8;               \
    }

    // ---- COMPUTE(buf): 8 MFMA on the 32-c tile ----
#define COMPUTE_(buf)                                                                \
    {                                                                                \
        const char* Ab = lds + (buf) * 20480;                                        \
        const char* Bb = Ab + 4096;                                                  \
        s16x8 a[2], bfr[4];                                                          \
        _Pragma("unroll")                                                            \
        for (int mf = 0; mf < 2; ++mf) {                                             \
            int pl_ = wm + mf * 16 + lm;                                             \
            a[mf] = *reinterpret_cast<const s16x8*>(                                 \
                Ab + pl_ * 64 + ((kq ^ ((pl_ >> 1) & 3)) << 4));                     \
        }                                                                            \
        _Pragma("unroll")                                                            \
        for (int nf = 0; nf < 4; ++nf) {                                             \
            int ol_ = wn + nf * 16 + lm;                                             \
            bfr[nf] = *reinterpret_cast<const s16x8*>(                               \
                Bb + ol_ * 64 + ((kq ^ ((ol_ >> 1) & 3)) << 4));                     \
        }                                                                            \
        _Pragma("unroll")                                                            \
        for (int mf = 0; mf < 2; ++mf)                                               \
            _Pragma("unroll")                                                        \
            for (int nf = 0; nf < 4; ++nf)                                           \
                acc[mf][nf] = __builtin_amdgcn_mfma_f32_16x16x32_bf16(               \
                    a[mf], bfr[nf], acc[mf][nf], 0, 0, 0);                           \
    }

    ISSUE_(0, 0);
    WRITE_(0);
    __syncthreads();

    int cur = 0;
#pragma unroll 1
    for (int t = 0; t < 72; ++t) {
        if (t < 71) ISSUE_(t + 1, cur ^ 1);
        COMPUTE_(cur);
        if (t < 71) WRITE_(cur ^ 1);
        __syncthreads();
        cur ^= 1;
    }
#undef ISSUE_
#undef WRITE_
#undef COMPUTE_

    // ---- epilogue: bias + store + GN partial ----
    float s = 0.f, sq = 0.f;
#pragma unroll
    for (int nf = 0; nf < 4; ++nf) {
        int oc = wn + nf * 16 + lm;
        float bv = bias[oc];
        float* orow = out + (b * CO_ + oc) * HW_ + hw0 + wm;
#pragma unroll
        for (int mf = 0; mf < 2; ++mf) {
            f32x4 r = acc[mf][nf];
            r.x += bv; r.y += bv; r.z += bv; r.w += bv;
            s  += r.x + r.y + r.z + r.w;
            sq += r.x * r.x + r.y * r.y + r.z * r.z + r.w * r.w;
            *reinterpret_cast<f32x4*>(orow + mf * 16 + kq * 4) = r;
        }
    }
#pragma unroll
    for (int o = 32; o > 0; o >>= 1) {
        s  += __shfl_down(s, o, 64);
        sq += __shfl_down(sq, o, 64);
    }
    if (lane == 0) { red[wv * 2] = s; red[wv * 2 + 1] = sq; }
    __syncthreads();
    if (tid == 0) {
        float S = 0.f, SQ = 0.f;
#pragma unroll
        for (int k = 0; k < 8; ++k) { S += red[k * 2]; SQ += red[k * 2 + 1]; }
        gnpart[blockIdx.x * 2]     = S;
        gnpart[blockIdx.x * 2 + 1] = SQ;
    }
}

// ---------------- K4: finalize stats. grid 4 (batch), 64 thr ----------------
__global__ void k_gn_stats(const float* __restrict__ part, float* __restrict__ stats) {
    int b = blockIdx.x, t = threadIdx.x;
    float2 v = reinterpret_cast<const float2*>(part)[b * 64 + t];
    float s = v.x, sq = v.y;
#pragma unroll
    for (int o = 32; o > 0; o >>= 1) {
        s  += __shfl_down(s, o, 64);
        sq += __shfl_down(sq, o, 64);
    }
    if (t == 0) {
        const float n = (float)(CO_ * HW_);
        float mean = s / n;
        float var  = sq / n - mean * mean;
        stats[b * 2] = mean;
        stats[b * 2 + 1] = rsqrtf(var + GN_EPS_);
    }
}

// ---------------- K5: normalize + affine + relu ----------------
__global__ void k_gn_apply(float* __restrict__ y, const float* __restrict__ stats,
                           const float* __restrict__ gamma, const float* __restrict__ beta) {
    int e4 = blockIdx.x * 256 + threadIdx.x;
    int b  = e4 >> 18;
    int oc = (e4 >> 10) & 255;
    float mean = stats[b * 2], rstd = stats[b * 2 + 1];
    float g  = gamma[oc] * rstd;
    float bb = beta[oc] - mean * g;
    float4* p = reinterpret_cast<float4*>(y);
    float4 v = p[e4];
    v.x = fmaxf(v.x * g + bb, 0.f);
    v.y = fmaxf(v.y * g + bb, 0.f);
    v.z = fmaxf(v.z * g + bb, 0.f);
    v.w = fmaxf(v.w * g + bb, 0.f);
    p[e4] = v;
}

extern "C" void kernel_launch(void* const* d_in, const int* in_sizes, int n_in,
                              void* d_out, int out_size, void* d_ws, size_t ws_size,
                              hipStream_t stream) {
    const float* x     = (const float*)d_in[0];
    const float* w_off = (const float*)d_in[1];
    const float* b_off = (const float*)d_in[2];
    const float* w     = (const float*)d_in[3];
    const float* bias  = (const float*)d_in[4];
    const float* gamma = (const float*)d_in[5];
    const float* beta  = (const float*)d_in[6];
    float* out = (float*)d_out;

    float* Wp     = (float*)d_ws;
    float* off    = Wp;                                 // 442368 floats
    short* wT     = (short*)(off + 27 * NPX_);          // 589824 shorts
    short* wOffT  = wT + 9 * 256 * 256;                 // 73728 shorts
    float* gnpart = (float*)(wOffT + 9 * 32 * 256);     // 512 floats
    float* stats  = gnpart + 512;                       // 8 floats
    short* xT     = (short*)(stats + 8);                // 4194304 shorts
    float* offp   = (float*)(xT + (long)NPX_ * 256);    // 4*27*NPX floats

    k_prep_w<<<256, 256, 0, stream>>>(w, wT);
    k_prep_woff<<<32, 256, 0, stream>>>(w_off, wOffT);
    k_xpose<<<1024, 256, 0, stream>>>(x, xT);
    k_offmfma<<<dim3(256, 4), 256, 0, stream>>>(xT, wOffT, offp);
    k_offreduce<<<1728, 256, 0, stream>>>(offp, b_off, off);
    k_fused<<<256, 512, 0, stream>>>(xT, off, wT, bias, out, gnpart);
    k_gn_stats<<<4, 64, 0, stream>>>(gnpart, stats);
    k_gn_apply<<<4096, 256, 0, stream>>>(out, stats, gamma, beta);
}

// Round 11
// 176.536 us; speedup vs baseline: 1.1120x; 1.1120x over previous
//
#include <hip/hip_runtime.h>

#define B_ 4
#define C_ 256
#define H_ 64
#define W_ 64
#define HW_ 4096
#define CO_ 256
#define NPX_ 16384
#define GN_EPS_ 1e-5f

typedef float f32x4 __attribute__((ext_vector_type(4)));
typedef short s16x8 __attribute__((ext_vector_type(8)));

__device__ __forceinline__ short f2bf(float f) {
    union { float f; unsigned u; } v; v.f = f;
    unsigned r = (v.u + 0x7FFFu + ((v.u >> 16) & 1u)) >> 16;
    return (short)(r & 0xFFFFu);
}
__device__ __forceinline__ float bf2f(short s) {
    union { unsigned u; float f; } v; v.u = ((unsigned)s & 0xFFFFu) << 16;
    return v.f;
}

__device__ __forceinline__ void gld_lds16(const void* g, void* l) {
    __builtin_amdgcn_global_load_lds(
        (const __attribute__((address_space(1))) unsigned*)g,
        (__attribute__((address_space(3))) unsigned*)l,
        16, 0, 0);
}

// ---------------- K0: w[oc][c][kk] -> wT[kk][oc][c] bf16 ----------------
__global__ void k_prep_w(const float* __restrict__ w, short* __restrict__ wT) {
    int oc = blockIdx.x, c = threadIdx.x;
    const float* src = w + (oc * 256 + c) * 9;
    float v[9];
#pragma unroll
    for (int t = 0; t < 9; ++t) v[t] = src[t];
#pragma unroll
    for (int t = 0; t < 9; ++t) wT[(t * 256 + oc) * 256 + c] = f2bf(v[t]);
}

// ---------------- K0a: w_off -> wOffT[kk][32][256] bf16 (rows 27..31 zero) ----
__global__ void k_prep_woff(const float* __restrict__ w_off, short* __restrict__ wOffT) {
    int o = blockIdx.x;
    int c = threadIdx.x;
    if (o < 27) {
        const float* src = w_off + (o * 256 + c) * 9;
#pragma unroll
        for (int t = 0; t < 9; ++t)
            wOffT[(t * 32 + o) * 256 + c] = f2bf(src[t]);
    } else {
#pragma unroll
        for (int t = 0; t < 9; ++t)
            wOffT[(t * 32 + o) * 256 + c] = 0;
    }
}

// ---------------- K0b: x[b][c][hw] f32 -> xT[b][hw][c] bf16 ----------------
__global__ void k_xpose(const float* __restrict__ x, short* __restrict__ xT) {
    __shared__ short T[64 * 72];

    int bx  = blockIdx.x;
    int px0 = (bx & 255) * 64;
    int c0  = (bx >> 8) * 64;
    int b   = px0 >> 12;
    int hw0 = px0 & 4095;

    int t  = threadIdx.x;
    int cl = t & 63;
    int q  = t >> 6;

    const float4* src = reinterpret_cast<const float4*>(
        x + (long)(b * 256 + c0 + cl) * 4096 + hw0);
#pragma unroll
    for (int j = 0; j < 4; ++j) {
        float4 v = src[j * 4 + q];
        int pl = (j * 4 + q) * 4;
        T[(pl + 0) * 72 + cl] = f2bf(v.x);
        T[(pl + 1) * 72 + cl] = f2bf(v.y);
        T[(pl + 2) * 72 + cl] = f2bf(v.z);
        T[(pl + 3) * 72 + cl] = f2bf(v.w);
    }
    __syncthreads();

    int pl = t >> 2;
    int s  = t & 3;
    short* dst = xT + (long)(px0 + pl) * 256 + c0 + s * 16;
    s16x8 a    = *reinterpret_cast<const s16x8*>(&T[pl * 72 + s * 16]);
    s16x8 bseg = *reinterpret_cast<const s16x8*>(&T[pl * 72 + s * 16 + 8]);
    *reinterpret_cast<s16x8*>(dst)     = a;
    *reinterpret_cast<s16x8*>(dst + 8) = bseg;
}

// ---------------- K1: offset conv via MFMA, K-split x4 ----------------
__global__ __launch_bounds__(256, 4) void k_offmfma(
        const short* __restrict__ xT, const short* __restrict__ wOffT,
        float* __restrict__ offp) {
    int tid  = threadIdx.x;
    int lane = tid & 63;
    int wv   = tid >> 6;

    int px0  = blockIdx.x * 64 + wv * 16;
    int cc0  = blockIdx.y * 64;
    int lm   = lane & 15;
    int lk   = cc0 + (lane >> 4) * 8;

    int pxA = px0 + lm;
    int h   = (pxA >> 6) & 63;
    int w   = pxA & 63;

    f32x4 acc[2];
    acc[0] = (f32x4)0.f; acc[1] = (f32x4)0.f;

#pragma unroll
    for (int kk = 0; kk < 9; ++kk) {
        const int ki = kk / 3, kj = kk % 3;
        int hh = h + ki - 1, ww = w + kj - 1;
        bool valid = ((unsigned)hh < 64u) & ((unsigned)ww < 64u);
        int srcpx = valid ? (pxA + (ki - 1) * 64 + (kj - 1)) : 0;
        const short* aP = xT + (long)srcpx * 256 + lk;
        const short* bP = wOffT + (long)(kk * 32 + lm) * 256 + lk;
#pragma unroll
        for (int ks = 0; ks < 2; ++ks) {
            s16x8 a = *reinterpret_cast<const s16x8*>(aP + ks * 32);
            if (!valid) a = (s16x8)0;
            s16x8 b0 = *reinterpret_cast<const s16x8*>(bP + ks * 32);
            s16x8 b1 = *reinterpret_cast<const s16x8*>(bP + 16 * 256 + ks * 32);
            acc[0] = __builtin_amdgcn_mfma_f32_16x16x32_bf16(a, b0, acc[0], 0, 0, 0);
            acc[1] = __builtin_amdgcn_mfma_f32_16x16x32_bf16(a, b1, acc[1], 0, 0, 0);
        }
    }

    float* op = offp + (long)blockIdx.y * 27 * NPX_;
#pragma unroll
    for (int nt = 0; nt < 2; ++nt) {
        int oc = nt * 16 + lm;
        if (oc < 27) {
#pragma unroll
            for (int j = 0; j < 4; ++j) {
                int px = px0 + (lane >> 4) * 4 + j;
                op[oc * NPX_ + px] = acc[nt][j];
            }
        }
    }
}

// ---------------- K1b: reduce K-split partials + bias ----------------
__global__ void k_offreduce(const float* __restrict__ offp, const float* __restrict__ b_off,
                            float* __restrict__ off) {
    int idx = blockIdx.x * 256 + threadIdx.x;
    int oc  = idx >> 14;
    float s = b_off[oc];
#pragma unroll
    for (int j = 0; j < 4; ++j) s += offp[(long)j * 27 * NPX_ + idx];
    off[idx] = s;
}

// ---------------- K2: FUSED sample + MFMA GEMM (round-8 structure, BK=64) ----------
// grid 256 XCD-swizzled: pxt = (bid&7)*32 + bid>>3 -> 32 consecutive rows per XCD.
// 512 thr = 8 waves. LDS exactly 81920 B -> 2 blocks/CU. 36 K-tiles (kk, c-quarter).
// Per tile: ISSUE(t+1) -> COMPUTE(t) -> WRITE(t+1) -> barrier.
__global__ __launch_bounds__(512, 4) void k_fused(
        const short* __restrict__ xT, const float* __restrict__ off,
        const short* __restrict__ wT, const float* __restrict__ bias,
        float* __restrict__ out, float* __restrict__ gnpart) {
    __shared__ __attribute__((aligned(16))) char lds[81920];  // 2 x (A 8K @0, B 32K @8K)

    int tid  = threadIdx.x;
    int lane = tid & 63;
    int wv   = tid >> 6;

    int bid = blockIdx.x;
    int pxt = (bid & 7) * 32 + (bid >> 3);     // bijective XCD swizzle (256 % 8 == 0)

    int px0 = pxt * 64;
    int b   = px0 >> 12;
    int hw0 = px0 & 4095;
    int h   = hw0 >> 6;
    long rb = (long)b * 4096;

    // sampling role: 8 threads per px, 64 c per tile
    int spx = tid >> 3;                  // 0..63 (= w coordinate)
    int j8  = (tid & 7) * 8;             // channel octet base within 64-c tile
    int pg  = px0 + spx;
    int abyte = spx * 128 + (((tid & 7) << 4) ^ ((spx & 7) << 4));

    // B staging constants
    int brow_lane = lane >> 3;           // row within 8-row group
    int bqg = (((lane & 7) ^ brow_lane) & 7) << 4;

    // mfma role
    int wm = (wv & 1) * 32;
    int wn = (wv >> 1) * 64;
    int lm = lane & 15;
    int kq = lane >> 4;

    const char* wTb = (const char*)wT;

    f32x4 acc[2][4];
#pragma unroll
    for (int i = 0; i < 2; ++i)
#pragma unroll
        for (int j = 0; j < 4; ++j) acc[i][j] = (f32x4)0.f;

    // persistent per-px sampling state (recomputed when kk changes)
    float sw00 = 0.f, sw01 = 0.f, sw10 = 0.f, sw11 = 0.f;
    const short *p00 = xT, *p01 = xT, *p10 = xT, *p11 = xT;

#define STAGE_(t, buf)                                                               \
    {                                                                                \
        int kk_ = (t) >> 2, cq_ = (t) & 3;                                           \
        if (((t) & 3) == 0) {                                                        \
            int ki_ = kk_ / 3, kj_ = kk_ % 3;                                        \
            float dy = off[(2 * kk_) * NPX_ + pg];                                   \
            float dx = off[(2 * kk_ + 1) * NPX_ + pg];                               \
            float mk = off[(18 + kk_) * NPX_ + pg];                                  \
            mk = 1.f / (1.f + __expf(-mk));                                          \
            float py  = (float)(h + ki_ - 1) + dy;                                   \
            float pxf = (float)(spx + kj_ - 1) + dx;                                 \
            float y0f = floorf(py), x0f = floorf(pxf);                               \
            float ly = py - y0f, lx = pxf - x0f;                                     \
            int y0 = (int)y0f, x0 = (int)x0f;                                        \
            int y1 = y0 + 1, x1 = x0 + 1;                                            \
            sw00 = (1.f - ly) * (1.f - lx) * mk;                                     \
            sw01 = (1.f - ly) * lx * mk;                                             \
            sw10 = ly * (1.f - lx) * mk;                                             \
            sw11 = ly * lx * mk;                                                     \
            bool vy0 = (y0 >= 0) & (y0 < H_);                                        \
            bool vy1 = (y1 >= 0) & (y1 < H_);                                        \
            bool vx0 = (x0 >= 0) & (x0 < W_);                                        \
            bool vx1 = (x1 >= 0) & (x1 < W_);                                        \
            if (!(vy0 & vx0)) sw00 = 0.f;                                            \
            if (!(vy0 & vx1)) sw01 = 0.f;                                            \
            if (!(vy1 & vx0)) sw10 = 0.f;                                            \
            if (!(vy1 & vx1)) sw11 = 0.f;                                            \
            int cy0 = min(max(y0, 0), H_ - 1), cy1 = min(max(y1, 0), H_ - 1);        \
            int cx0 = min(max(x0, 0), W_ - 1), cx1 = min(max(x1, 0), W_ - 1);        \
            p00 = xT + (rb + cy0 * 64 + cx0) * 256;                                  \
            p01 = xT + (rb + cy0 * 64 + cx1) * 256;                                  \
            p10 = xT + (rb + cy1 * 64 + cx0) * 256;                                  \
            p11 = xT + (rb + cy1 * 64 + cx1) * 256;                                  \
        }                                                                            \
        _Pragma("unroll")                                                            \
        for (int g = 0; g < 4; ++g) {                                                \
            int row8 = wv * 4 + g;               /* 8-oc-row group 0..31 */          \
            int ocr  = row8 * 8 + brow_lane;                                         \
            const char* srcB = wTb + ((long)(kk_ * 256 + ocr) << 9)                  \
                               + cq_ * 128 + bqg;                                    \
            gld_lds16(srcB, (void*)(lds + (buf) * 40960 + 8192 + row8 * 1024));      \
        }                                                                            \
        int coff = cq_ * 64 + j8;                                                    \
        s16x8 r00 = *reinterpret_cast<const s16x8*>(p00 + coff);                     \
        s16x8 r01 = *reinterpret_cast<const s16x8*>(p01 + coff);                     \
        s16x8 r10 = *reinterpret_cast<const s16x8*>(p10 + coff);                     \
        s16x8 r11 = *reinterpret_cast<const s16x8*>(p11 + coff);                     \
        s16x8 o8;                                                                    \
        _Pragma("unroll")                                                            \
        for (int jj = 0; jj < 8; ++jj) {                                             \
            float g2 = sw00 * bf2f(r00[jj]) + sw01 * bf2f(r01[jj])                   \
                     + sw10 * bf2f(r10[jj]) + sw11 * bf2f(r11[jj]);                  \
            o8[jj] = f2bf(g2);                                                       \
        }                                                                            \
        *reinterpret_cast<s16x8*>(lds + (buf) * 40960 + abyte) = o8;                 \
    }

#define COMPUTE_(buf)                                                                \
    {                                                                                \
        const char* Ab = lds + (buf) * 40960;                                        \
        const char* Bb = lds + (buf) * 40960 + 8192;                                 \
        _Pragma("unroll")                                                            \
        for (int ksub = 0; ksub < 2; ++ksub) {                                       \
            int cb_ = ksub * 64 + kq * 16;                                           \
            s16x8 a[2], bfr[4];                                                      \
            _Pragma("unroll")                                                        \
            for (int mf = 0; mf < 2; ++mf) {                                         \
                int pl_ = wm + mf * 16 + lm;                                         \
                a[mf] = *reinterpret_cast<const s16x8*>(                             \
                    Ab + pl_ * 128 + (cb_ ^ ((pl_ & 7) << 4)));                      \
            }                                                                        \
            _Pragma("unroll")                                                        \
            for (int nf = 0; nf < 4; ++nf) {                                         \
                int ol_ = wn + nf * 16 + lm;                                         \
                bfr[nf] = *reinterpret_cast<const s16x8*>(                           \
                    Bb + ol_ * 128 + (cb_ ^ ((ol_ & 7) << 4)));                      \
            }                                                                        \
            _Pragma("unroll")                                                        \
            for (int mf = 0; mf < 2; ++mf)                                           \
                _Pragma("unroll")                                                    \
                for (int nf = 0; nf < 4; ++nf)                                       \
                    acc[mf][nf] = __builtin_amdgcn_mfma_f32_16x16x32_bf16(           \
                        a[mf], bfr[nf], acc[mf][nf], 0, 0, 0);                       \
        }                                                                            \
    }

    STAGE_(0, 0);
    __syncthreads();

    int cur = 0;
#pragma unroll 1
    for (int t = 0; t < 36; ++t) {
        if (t < 35) STAGE_(t + 1, cur ^ 1);
        COMPUTE_(cur);
        __syncthreads();
        cur ^= 1;
    }
#undef STAGE_
#undef COMPUTE_

    // ---- epilogue: bias + store + GN partial (red[] reuses lds after last barrier) ----
    float* red = (float*)lds;
    float s = 0.f, sq = 0.f;
#pragma unroll
    for (int nf = 0; nf < 4; ++nf) {
        int oc = wn + nf * 16 + lm;
        float bv = bias[oc];
        float* orow = out + (b * CO_ + oc) * HW_ + hw0 + wm;
#pragma unroll
        for (int mf = 0; mf < 2; ++mf) {
            f32x4 r = acc[mf][nf];
            r.x += bv; r.y += bv; r.z += bv; r.w += bv;
            s  += r.x + r.y + r.z + r.w;
            sq += r.x * r.x + r.y * r.y + r.z * r.z + r.w * r.w;
            *reinterpret_cast<f32x4*>(orow + mf * 16 + kq * 4) = r;
        }
    }
#pragma unroll
    for (int o = 32; o > 0; o >>= 1) {
        s  += __shfl_down(s, o, 64);
        sq += __shfl_down(sq, o, 64);
    }
    if (lane == 0) { red[wv * 2] = s; red[wv * 2 + 1] = sq; }
    __syncthreads();
    if (tid == 0) {
        float S = 0.f, SQ = 0.f;
#pragma unroll
        for (int k = 0; k < 8; ++k) { S += red[k * 2]; SQ += red[k * 2 + 1]; }
        gnpart[pxt * 2]     = S;
        gnpart[pxt * 2 + 1] = SQ;
    }
}

// ---------------- K4: finalize stats. grid 4 (batch), 64 thr ----------------
__global__ void k_gn_stats(const float* __restrict__ part, float* __restrict__ stats) {
    int b = blockIdx.x, t = threadIdx.x;
    float2 v = reinterpret_cast<const float2*>(part)[b * 64 + t];
    float s = v.x, sq = v.y;
#pragma unroll
    for (int o = 32; o > 0; o >>= 1) {
        s  += __shfl_down(s, o, 64);
        sq += __shfl_down(sq, o, 64);
    }
    if (t == 0) {
        const float n = (float)(CO_ * HW_);
        float mean = s / n;
        float var  = sq / n - mean * mean;
        stats[b * 2] = mean;
        stats[b * 2 + 1] = rsqrtf(var + GN_EPS_);
    }
}

// ---------------- K5: normalize + affine + relu ----------------
__global__ void k_gn_apply(float* __restrict__ y, const float* __restrict__ stats,
                           const float* __restrict__ gamma, const float* __restrict__ beta) {
    int e4 = blockIdx.x * 256 + threadIdx.x;
    int b  = e4 >> 18;
    int oc = (e4 >> 10) & 255;
    float mean = stats[b * 2], rstd = stats[b * 2 + 1];
    float g  = gamma[oc] * rstd;
    float bb = beta[oc] - mean * g;
    float4* p = reinterpret_cast<float4*>(y);
    float4 v = p[e4];
    v.x = fmaxf(v.x * g + bb, 0.f);
    v.y = fmaxf(v.y * g + bb, 0.f);
    v.z = fmaxf(v.z * g + bb, 0.f);
    v.w = fmaxf(v.w * g + bb, 0.f);
    p[e4] = v;
}

extern "C" void kernel_launch(void* const* d_in, const int* in_sizes, int n_in,
                              void* d_out, int out_size, void* d_ws, size_t ws_size,
                              hipStream_t stream) {
    const float* x     = (const float*)d_in[0];
    const float* w_off = (const float*)d_in[1];
    const float* b_off = (const float*)d_in[2];
    const float* w     = (const float*)d_in[3];
    const float* bias  = (const float*)d_in[4];
    const float* gamma = (const float*)d_in[5];
    const float* beta  = (const float*)d_in[6];
    float* out = (float*)d_out;

    float* Wp     = (float*)d_ws;
    float* off    = Wp;                                 // 442368 floats
    short* wT     = (short*)(off + 27 * NPX_);          // 589824 shorts
    short* wOffT  = wT + 9 * 256 * 256;                 // 73728 shorts
    float* gnpart = (float*)(wOffT + 9 * 32 * 256);     // 512 floats
    float* stats  = gnpart + 512;                       // 8 floats
    short* xT     = (short*)(stats + 8);                // 4194304 shorts
    float* offp   = (float*)(xT + (long)NPX_ * 256);    // 4*27*NPX floats

    k_prep_w<<<256, 256, 0, stream>>>(w, wT);
    k_prep_woff<<<32, 256, 0, stream>>>(w_off, wOffT);
    k_xpose<<<1024, 256, 0, stream>>>(x, xT);
    k_offmfma<<<dim3(256, 4), 256, 0, stream>>>(xT, wOffT, offp);
    k_offreduce<<<1728, 256, 0, stream>>>(offp, b_off, off);
    k_fused<<<256, 512, 0, stream>>>(xT, off, wT, bias, out, gnpart);
    k_gn_stats<<<4, 64, 0, stream>>>(gnpart, stats);
    k_gn_apply<<<4096, 256, 0, stream>>>(out, stats, gamma, beta);
}